// Round 4
// baseline (357.908 us; speedup 1.0000x reference)
//
#include <hip/hip_runtime.h>
#include <math.h>

#define NB 96
#define NB2 (NB * NB)
#define DFEAT 64
#define NCLS 21
#define MARGIN 0.3

typedef int i4 __attribute__((ext_vector_type(4)));  // native vec for nontemporal builtin
typedef unsigned int u32;

// ---------------------------------------------------------------------------
// Kernel A: per (i,j) pair compute (all f64 so boolean compares vs the float64
// numpy reference are effectively exact):
//   mat[i,j]   = -cos_sim(logits_i, feat2_j)
//   thr[i,j]   = MARGIN + mat[i,j]
//   share[i,j] = (labels_i . labels_j) > 0
// ---------------------------------------------------------------------------
__global__ void precompute_kernel(const float* __restrict__ logits,
                                  const float* __restrict__ labels,
                                  const float* __restrict__ feat2,
                                  double* __restrict__ mat,
                                  double* __restrict__ thr,
                                  unsigned char* __restrict__ share) {
    int gid = blockIdx.x * blockDim.x + threadIdx.x;
    if (gid >= NB2) return;
    int i = gid / NB;
    int j = gid - i * NB;

    const float* xi = logits + i * DFEAT;
    const float* yj = feat2 + j * DFEAT;
    double nx = 0.0, ny = 0.0, dot = 0.0;
#pragma unroll
    for (int d = 0; d < DFEAT; ++d) {
        double a = (double)xi[d];
        double b = (double)yj[d];
        nx += a * a;
        ny += b * b;
        dot += a * b;
    }
    nx = fmax(sqrt(nx), 1e-12);
    ny = fmax(sqrt(ny), 1e-12);
    double m = -(dot / (nx * ny));
    mat[gid] = m;
    thr[gid] = MARGIN + m;

    const float* li = labels + i * NCLS;
    const float* lj = labels + j * NCLS;
    float ldot = 0.f;
#pragma unroll
    for (int c = 0; c < NCLS; ++c) ldot += li[c] * lj[c];
    share[gid] = (ldot > 0.f) ? 1 : 0;
}

// ---------------------------------------------------------------------------
// Kernel A2: all boolean outcomes precomputed as 96-bit rows.
//   rowmask[i][p][n] = !share[i,n] && (mat[i,n] <= MARGIN + mat[i,p])
// Stored as uint4-strided words (mask4[(i*96+p)*4 + w]), bit n -> word n>>5,
// bit n&31. 9216 rows x 16 B = 147 KB (L2-resident for kernel B).
// ---------------------------------------------------------------------------
__global__ void mask_kernel(const double* __restrict__ mat,
                            const double* __restrict__ thr,
                            const unsigned char* __restrict__ share,
                            u32* __restrict__ mask4) {
    int gid = blockIdx.x * blockDim.x + threadIdx.x;
    if (gid >= NB2) return;
    int i = gid / NB;
    double t = thr[gid];
    const double* mrow = mat + i * NB;
    const unsigned char* srow = share + i * NB;
    u32 w0 = 0, w1 = 0, w2 = 0;
#pragma unroll
    for (int n = 0; n < 32; ++n)
        if (!srow[n] && (mrow[n] <= t)) w0 |= (1u << n);
#pragma unroll
    for (int n = 0; n < 32; ++n)
        if (!srow[32 + n] && (mrow[32 + n] <= t)) w1 |= (1u << n);
#pragma unroll
    for (int n = 0; n < 32; ++n)
        if (!srow[64 + n] && (mrow[64 + n] <= t)) w2 |= (1u << n);
    mask4[gid * 4 + 0] = w0;
    mask4[gid * 4 + 1] = w1;
    mask4[gid * 4 + 2] = w2;
    mask4[gid * 4 + 3] = 0;
}

// ---------------------------------------------------------------------------
// Kernel B: one block per (i,j); writes the 96x96 (k,n) int32 0/1 slab.
// Per k, the whole n-row is either zero or rowmask[i][p] with
// p = argmax(mat[i,j], mat[i,k]). Inner loop: 1 LDS word read + bit extract
// + nontemporal int4 store. No f64 anywhere near the store stream.
// ---------------------------------------------------------------------------
__global__ __launch_bounds__(256) void quad_kernel(const double* __restrict__ thr,
                                                   const unsigned char* __restrict__ share,
                                                   const u32* __restrict__ mask4,
                                                   int* __restrict__ out) {
    const int bid = blockIdx.x;
    const int i = bid / NB;
    const int j = bid - i * NB;
    const int tid = threadIdx.x;

    __shared__ u32 vrow[NB][4];  // per-k row mask (already validity-masked)

    if (tid < NB) {
        const int k = tid;
        const double thr_j = thr[i * NB + j];
        const bool sames_ij = share[i * NB + j] && (j != i);
        const bool ok = sames_ij && share[i * NB + k] && (k != i) && (j < k);
        u32 r0 = 0, r1 = 0, r2 = 0;
        if (ok) {
            int p = (thr[i * NB + k] > thr_j) ? k : j;  // argmax mat -> argmax thr
            const u32* mp = mask4 + (size_t)(i * NB + p) * 4;
            r0 = mp[0]; r1 = mp[1]; r2 = mp[2];
        }
        vrow[k][0] = r0; vrow[k][1] = r1; vrow[k][2] = r2; vrow[k][3] = 0;
    }
    __syncthreads();

    i4* outp = (i4*)(out + (size_t)bid * (size_t)NB2);

    // 96 k-rows * 24 int4-chunks per row = 2304 chunks; 256 threads -> 9 each.
#pragma unroll
    for (int r = 0; r < 9; ++r) {
        int c = r * 256 + tid;
        int k = c / 24;
        int q = c - k * 24;          // chunk within row: covers n = 4q..4q+3
        u32 w = vrow[k][q >> 3];     // word holding these 4 bits
        u32 b = w >> ((q & 7) * 4);
        i4 v;
        v.x = (int)(b & 1u);
        v.y = (int)((b >> 1) & 1u);
        v.z = (int)((b >> 2) & 1u);
        v.w = (int)((b >> 3) & 1u);
        __builtin_nontemporal_store(v, &outp[c]);
    }
}

extern "C" void kernel_launch(void* const* d_in, const int* in_sizes, int n_in,
                              void* d_out, int out_size, void* d_ws, size_t ws_size,
                              hipStream_t stream) {
    const float* logits = (const float*)d_in[0]; // [96,64]
    const float* labels = (const float*)d_in[1]; // [96,21]
    const float* feat2  = (const float*)d_in[2]; // [96,64]
    int* out = (int*)d_out;                      // [96,96,96,96] as 0/1 int32

    double* mat = (double*)d_ws;                        // 9216 doubles (73.7 KB)
    double* thr = mat + NB2;                            // 9216 doubles
    unsigned char* share = (unsigned char*)(thr + NB2); // 9216 bytes
    // align mask4 to 16 B
    size_t off = (size_t)(share + NB2 - (unsigned char*)d_ws);
    off = (off + 15) & ~(size_t)15;
    u32* mask4 = (u32*)((unsigned char*)d_ws + off);    // 9216*4 u32 (147 KB)

    precompute_kernel<<<(NB2 + 255) / 256, 256, 0, stream>>>(logits, labels, feat2,
                                                             mat, thr, share);
    mask_kernel<<<(NB2 + 255) / 256, 256, 0, stream>>>(mat, thr, share, mask4);
    quad_kernel<<<NB2, 256, 0, stream>>>(thr, share, mask4, out);
}

// Round 5
// 350.281 us; speedup vs baseline: 1.0218x; 1.0218x over previous
//
#include <hip/hip_runtime.h>
#include <math.h>

#define NB 96
#define NB2 (NB * NB)
#define DFEAT 64
#define NCLS 21
#define MARGIN 0.3

typedef int i4 __attribute__((ext_vector_type(4)));
typedef unsigned int u32;

// ---------------------------------------------------------------------------
// Kernel A: per (i,j) pair, all f64 (boolean compares vs float64 numpy ref
// must be effectively exact):
//   mat[i,j]   = -cos_sim(logits_i, feat2_j)
//   share[i,j] = (labels_i . labels_j) > 0
// ---------------------------------------------------------------------------
__global__ void precompute_kernel(const float* __restrict__ logits,
                                  const float* __restrict__ labels,
                                  const float* __restrict__ feat2,
                                  double* __restrict__ mat,
                                  unsigned char* __restrict__ share) {
    int gid = blockIdx.x * blockDim.x + threadIdx.x;
    if (gid >= NB2) return;
    int i = gid / NB;
    int j = gid - i * NB;

    const float* xi = logits + i * DFEAT;
    const float* yj = feat2 + j * DFEAT;
    double nx = 0.0, ny = 0.0, dot = 0.0;
#pragma unroll
    for (int d = 0; d < DFEAT; ++d) {
        double a = (double)xi[d];
        double b = (double)yj[d];
        nx += a * a;
        ny += b * b;
        dot += a * b;
    }
    nx = fmax(sqrt(nx), 1e-12);
    ny = fmax(sqrt(ny), 1e-12);
    mat[gid] = -(dot / (nx * ny));

    const float* li = labels + i * NCLS;
    const float* lj = labels + j * NCLS;
    float ldot = 0.f;
#pragma unroll
    for (int c = 0; c < NCLS; ++c) ldot += li[c] * lj[c];
    share[gid] = (ldot > 0.f) ? 1 : 0;
}

// ---------------------------------------------------------------------------
// Kernel A2: rowmask[i][p][n] = !share[i,n] && (mat[i,n] <= MARGIN + mat[i,p])
// One block per i; mat row staged in LDS (broadcast reads), one thread per p.
// 96 blocks x 128 threads -> latency fully hidden.
// ---------------------------------------------------------------------------
__global__ __launch_bounds__(128) void mask_kernel(const double* __restrict__ mat,
                                                   const unsigned char* __restrict__ share,
                                                   u32* __restrict__ mask4) {
    const int i = blockIdx.x;
    const int p = threadIdx.x;
    __shared__ double sm[NB];
    __shared__ u32 sdiff[3];

    if (p < NB) sm[p] = mat[i * NB + p];
    if (p < 3) {
        u32 w = 0;
        const unsigned char* srow = share + i * NB + p * 32;
#pragma unroll
        for (int n = 0; n < 32; ++n)
            if (!srow[n]) w |= (1u << n);
        sdiff[p] = w;
    }
    __syncthreads();
    if (p >= NB) return;

    const double t = MARGIN + sm[p];
    u32 w0 = 0, w1 = 0, w2 = 0;
#pragma unroll
    for (int n = 0; n < 32; ++n) if (sm[n] <= t)      w0 |= (1u << n);
#pragma unroll
    for (int n = 0; n < 32; ++n) if (sm[32 + n] <= t) w1 |= (1u << n);
#pragma unroll
    for (int n = 0; n < 32; ++n) if (sm[64 + n] <= t) w2 |= (1u << n);

    const int gid = i * NB + p;
    mask4[gid * 4 + 0] = w0 & sdiff[0];
    mask4[gid * 4 + 1] = w1 & sdiff[1];
    mask4[gid * 4 + 2] = w2 & sdiff[2];
    mask4[gid * 4 + 3] = 0;
}

// ---------------------------------------------------------------------------
// Kernel B: one block per (i,j); writes the 96x96 (k,n) int32 0/1 slab.
// Per k the row is zero or rowmask[i][argmax(mat[i,j],mat[i,k])].
// Plain (cached) dwordx4 stores — regular stores hit the measured 6.3 TB/s
// streaming ceiling; nt was the round-3/4 suspect.
// ---------------------------------------------------------------------------
__global__ __launch_bounds__(256) void quad_kernel(const double* __restrict__ mat,
                                                   const unsigned char* __restrict__ share,
                                                   const u32* __restrict__ mask4,
                                                   int* __restrict__ out) {
    const int bid = blockIdx.x;
    const int i = bid / NB;
    const int j = bid - i * NB;
    const int tid = threadIdx.x;

    __shared__ u32 vrow[NB][4];  // per-k row mask (already validity-masked)

    if (tid < NB) {
        const int k = tid;
        const double mat_j = mat[i * NB + j];
        const bool sames_ij = share[i * NB + j] && (j != i);
        const bool ok = sames_ij && share[i * NB + k] && (k != i) && (j < k);
        u32 r0 = 0, r1 = 0, r2 = 0;
        if (ok) {
            int p = (mat[i * NB + k] > mat_j) ? k : j;  // argmax mat[i,p]
            const u32* mp = mask4 + (size_t)(i * NB + p) * 4;
            r0 = mp[0]; r1 = mp[1]; r2 = mp[2];
        }
        vrow[k][0] = r0; vrow[k][1] = r1; vrow[k][2] = r2; vrow[k][3] = 0;
    }
    __syncthreads();

    i4* outp = (i4*)(out + (size_t)bid * (size_t)NB2);

    // 96 k-rows * 24 int4-chunks per row = 2304 chunks; 256 threads -> 9 each.
#pragma unroll
    for (int r = 0; r < 9; ++r) {
        int c = r * 256 + tid;
        int k = c / 24;
        int q = c - k * 24;          // chunk within row: covers n = 4q..4q+3
        u32 w = vrow[k][q >> 3];     // broadcast within 8-lane groups: no conflict
        u32 b = w >> ((q & 7) * 4);
        i4 v;
        v.x = (int)(b & 1u);
        v.y = (int)((b >> 1) & 1u);
        v.z = (int)((b >> 2) & 1u);
        v.w = (int)((b >> 3) & 1u);
        outp[c] = v;
    }
}

extern "C" void kernel_launch(void* const* d_in, const int* in_sizes, int n_in,
                              void* d_out, int out_size, void* d_ws, size_t ws_size,
                              hipStream_t stream) {
    const float* logits = (const float*)d_in[0]; // [96,64]
    const float* labels = (const float*)d_in[1]; // [96,21]
    const float* feat2  = (const float*)d_in[2]; // [96,64]
    int* out = (int*)d_out;                      // [96,96,96,96] as 0/1 int32

    double* mat = (double*)d_ws;                        // 9216 doubles (73.7 KB)
    unsigned char* share = (unsigned char*)(mat + NB2); // 9216 bytes
    size_t off = (size_t)(share + NB2 - (unsigned char*)d_ws);
    off = (off + 15) & ~(size_t)15;
    u32* mask4 = (u32*)((unsigned char*)d_ws + off);    // 9216*4 u32 (147 KB)

    precompute_kernel<<<(NB2 + 255) / 256, 256, 0, stream>>>(logits, labels, feat2,
                                                             mat, share);
    mask_kernel<<<NB, 128, 0, stream>>>(mat, share, mask4);
    quad_kernel<<<NB2, 256, 0, stream>>>(mat, share, mask4, out);
}